// Round 1
// baseline (761.790 us; speedup 1.0000x reference)
//
#include <hip/hip_runtime.h>

typedef float v4 __attribute__((ext_vector_type(4)));
typedef float v2 __attribute__((ext_vector_type(2)));
typedef int  iv4 __attribute__((ext_vector_type(4)));

#define NEGV 1000000000000.0f
#define SEQ 512
#define NL 20
#define LOGITS_ELEMS (16 * 20 * 512 * 512)   // 83,886,080

// ---------------------------------------------------------------------------
// Kernel 1: out = x @ [w1 | w2] + [b1 | b2]; RoPE the w1-half into qw,kw
// (deinterleaved); store the w2-half transposed/2 as dense[b][40][S].
// 128 threads, BM=32, BN=64, 4x4 micro-tile (2 B LDS per lane-FMA).
// grid (3, 256): jb=0,1 -> w1 cols, jb=2 -> w2 cols.
// ---------------------------------------------------------------------------
__global__ __launch_bounds__(128)
void prep_kernel(const float* __restrict__ x, const float* __restrict__ w1,
                 const float* __restrict__ b1, const float* __restrict__ w2,
                 const float* __restrict__ b2,
                 float* __restrict__ qw, float* __restrict__ kw,
                 float* __restrict__ dense)
{
    __shared__ float xs[32][36];    // pad 36: 16B-aligned rows, conflict-free
    __shared__ float wsm[32][64];   // [k][n]

    const int tid = threadIdx.x;
    const int jb = blockIdx.x;           // 0..2
    const int m0 = blockIdx.y * 32;      // global row block
    const int j0 = jb * 64;

    const int tx = tid & 15;             // col group: cols 4tx..4tx+3
    const int ty = tid >> 4;             // 0..7: rows 4ty..4ty+3

    const int sxm = tid >> 2;            // 0..31
    const int sxk = (tid & 3) * 8;       // 0,8,16,24
    const int swk = tid >> 2;            // 0..31 (k)
    const int swn = (tid & 3) * 16;      // 0,16,32,48

    float acc[4][4] = {};

    for (int k0 = 0; k0 < 768; k0 += 32) {
        v4 xa = *(const v4*)&x[(size_t)(m0 + sxm) * 768 + k0 + sxk];
        v4 xb = *(const v4*)&x[(size_t)(m0 + sxm) * 768 + k0 + sxk + 4];
        v4 wv[4];
        if (jb < 2) {
            const float* wp = &w1[(size_t)(k0 + swk) * 128 + j0 + swn];
#pragma unroll
            for (int t = 0; t < 4; ++t) wv[t] = *(const v4*)(wp + 4 * t);
        } else {
            const float* wp = &w2[(size_t)(k0 + swk) * 40 + swn];
#pragma unroll
            for (int t = 0; t < 4; ++t) {
                if (swn + 4 * t < 40) wv[t] = *(const v4*)(wp + 4 * t);
                else                  wv[t] = 0.0f;
            }
        }
        __syncthreads();
        *(v4*)&xs[sxm][sxk] = xa;
        *(v4*)&xs[sxm][sxk + 4] = xb;
#pragma unroll
        for (int t = 0; t < 4; ++t) *(v4*)&wsm[swk][swn + 4 * t] = wv[t];
        __syncthreads();
#pragma unroll
        for (int k = 0; k < 32; k += 4) {
            v4 a0 = *(const v4*)&xs[4 * ty + 0][k];
            v4 a1 = *(const v4*)&xs[4 * ty + 1][k];
            v4 a2 = *(const v4*)&xs[4 * ty + 2][k];
            v4 a3 = *(const v4*)&xs[4 * ty + 3][k];
            v4 b0v = *(const v4*)&wsm[k + 0][tx * 4];
            v4 b1v = *(const v4*)&wsm[k + 1][tx * 4];
            v4 b2v = *(const v4*)&wsm[k + 2][tx * 4];
            v4 b3v = *(const v4*)&wsm[k + 3][tx * 4];
#pragma unroll
            for (int j = 0; j < 4; ++j) {
                acc[0][j] += a0[0] * b0v[j] + a0[1] * b1v[j] + a0[2] * b2v[j] + a0[3] * b3v[j];
                acc[1][j] += a1[0] * b0v[j] + a1[1] * b1v[j] + a1[2] * b2v[j] + a1[3] * b3v[j];
                acc[2][j] += a2[0] * b0v[j] + a2[1] * b1v[j] + a2[2] * b2v[j] + a2[3] * b3v[j];
                acc[3][j] += a3[0] * b0v[j] + a3[1] * b1v[j] + a3[2] * b2v[j] + a3[3] * b3v[j];
            }
        }
    }

    if (jb < 2) {
        // cols j = j0+4tx .. +3 = {q[2p], k[2p], q[2p+1], k[2p+1]}, p = j0/4+tx
        const int p = (j0 >> 2) + tx;
        const float fr = __powf(10000.0f, (float)(-2 * p) / 64.0f);
        v4 bb = *(const v4*)&b1[j0 + tx * 4];
#pragma unroll
        for (int i = 0; i < 4; ++i) {
            const int mrow = m0 + 4 * ty + i;        // global row = b*512+s
            const int s = mrow & 511;
            float ang = (float)s * fr;
            float sn = sinf(ang), cs = cosf(ang);
            float q0  = acc[i][0] + bb[0];
            float k0v = acc[i][1] + bb[1];
            float q1  = acc[i][2] + bb[2];
            float k1v = acc[i][3] + bb[3];
            v2 qo, ko;
            qo[0] = q0 * cs - q1 * sn;   qo[1] = q1 * cs + q0 * sn;
            ko[0] = k0v * cs - k1v * sn; ko[1] = k1v * cs + k0v * sn;
            *(v2*)&qw[(size_t)mrow * 64 + 2 * p] = qo;
            *(v2*)&kw[(size_t)mrow * 64 + 2 * p] = ko;
        }
    } else if (tx < 10) {
        // dense cols jd = 4tx..4tx+3 (0..39), store dense[b][jd][s] = (v+b2)/2
        v4 bb = *(const v4*)&b2[tx * 4];
#pragma unroll
        for (int i = 0; i < 4; ++i) {
            const int mrow = m0 + 4 * ty + i;
            const int bi = mrow >> 9;
            const int s = mrow & 511;
#pragma unroll
            for (int j = 0; j < 4; ++j) {
                dense[(size_t)(bi * 40 + tx * 4 + j) * 512 + s] = (acc[i][j] + bb[j]) * 0.5f;
            }
        }
    }
}

// ---------------------------------------------------------------------------
// Kernel 2: one block per (b, 32-row m-tile) = 256 blocks.
// Phase 1: qk[32][512] = qw . kw^T / 8 into LDS (8 n-chunks of 64).
// Phase 2: for each l, stream rows contiguously: 256 threads = 2 full rows
// of 512 cols -> every wave stores 1 KB contiguous; 64 KB sequential runs
// per (b,l) plane per output. Nontemporal stores (write-once data).
// ---------------------------------------------------------------------------
__global__ __launch_bounds__(256)
void fused_kernel(const float* __restrict__ qw, const float* __restrict__ kw,
                  const float* __restrict__ dense, const int* __restrict__ mask,
                  float* __restrict__ outL, float* __restrict__ outP)
{
    __shared__ float qkS[32][516];  // qk/8; pad 516 (mod32=4) spreads rows over banks
    __shared__ float qwL[32][68];   // [m][k]
    __shared__ float kwT[64][64];   // [k][n] for one 64-col chunk
    __shared__ float dOs[20][32];   // dense odd rows over m-tile
    __shared__ float mMs[32];

    const int tid = threadIdx.x;
    const int m0 = blockIdx.x * 32;
    const int b  = blockIdx.y;

    // one-time staging: qw tile, dense odd rows, m-mask
    {
        const int m = tid >> 3, kk = (tid & 7) * 8;
        v4 a = *(const v4*)&qw[(size_t)(b * SEQ + m0 + m) * 64 + kk];
        v4 c = *(const v4*)&qw[(size_t)(b * SEQ + m0 + m) * 64 + kk + 4];
        *(v4*)&qwL[m][kk] = a;
        *(v4*)&qwL[m][kk + 4] = c;
    }
#pragma unroll
    for (int t = 0; t < 3; ++t) {
        int flat = t * 256 + tid;
        if (flat < 640) {
            int l = flat >> 5, m = flat & 31;
            dOs[l][m] = dense[(size_t)(b * 40 + 2 * l + 1) * 512 + m0 + m];
        }
    }
    if (tid < 32) mMs[tid] = (float)mask[b * SEQ + m0 + tid];

    // ---- phase 1: qk strip into LDS ----
    const int txc = tid & 15;   // n/4 within chunk
    const int r   = tid >> 4;   // rows r, r+16
    const int kn  = tid >> 2;   // staging: n 0..63
    const int kkk = (tid & 3) * 16;

    for (int nc = 0; nc < 8; ++nc) {
        const int n0 = nc * 64;
        v4 kv[4];
#pragma unroll
        for (int t = 0; t < 4; ++t)
            kv[t] = *(const v4*)&kw[(size_t)(b * SEQ + n0 + kn) * 64 + kkk + 4 * t];
        __syncthreads();   // prior chunk's kwT readers done
#pragma unroll
        for (int t = 0; t < 4; ++t) {
            kwT[kkk + 4 * t + 0][kn] = kv[t][0];
            kwT[kkk + 4 * t + 1][kn] = kv[t][1];
            kwT[kkk + 4 * t + 2][kn] = kv[t][2];
            kwT[kkk + 4 * t + 3][kn] = kv[t][3];
        }
        __syncthreads();

        float acc0[4] = {0.f, 0.f, 0.f, 0.f};
        float acc1[4] = {0.f, 0.f, 0.f, 0.f};
#pragma unroll
        for (int k = 0; k < 64; k += 4) {
            v4 a0 = *(const v4*)&qwL[r][k];
            v4 a1 = *(const v4*)&qwL[r + 16][k];
            v4 bv0 = *(const v4*)&kwT[k + 0][txc * 4];
            v4 bv1 = *(const v4*)&kwT[k + 1][txc * 4];
            v4 bv2 = *(const v4*)&kwT[k + 2][txc * 4];
            v4 bv3 = *(const v4*)&kwT[k + 3][txc * 4];
#pragma unroll
            for (int j = 0; j < 4; ++j) {
                acc0[j] += a0[0] * bv0[j] + a0[1] * bv1[j] + a0[2] * bv2[j] + a0[3] * bv3[j];
                acc1[j] += a1[0] * bv0[j] + a1[1] * bv1[j] + a1[2] * bv2[j] + a1[3] * bv3[j];
            }
        }
        v4 o0, o1;
#pragma unroll
        for (int j = 0; j < 4; ++j) { o0[j] = acc0[j] * 0.125f; o1[j] = acc1[j] * 0.125f; }
        *(v4*)&qkS[r][n0 + txc * 4] = o0;
        *(v4*)&qkS[r + 16][n0 + txc * 4] = o1;
    }
    __syncthreads();

    // ---- phase 2: stream 20 l-planes with contiguous-row stores ----
    const int c    = tid & 127;      // col chunk: cols 4c..4c+3
    const int half = tid >> 7;       // 0,1: row parity within pair
    const int gn0  = c * 4;

    iv4 mi = *(const iv4*)&mask[b * SEQ + gn0];
    v4 mNv, cN;
#pragma unroll
    for (int j = 0; j < 4; ++j) {
        mNv[j] = (float)mi[j];
        cN[j] = -NEGV * (1.0f - mNv[j]);
    }

    for (int l = 0; l < NL; ++l) {
        v4 de = *(const v4*)&dense[(size_t)(b * 40 + 2 * l) * 512 + gn0];
        const size_t lbase = ((size_t)(b * NL + l) * SEQ + m0) * SEQ + gn0;
#pragma unroll
        for (int it = 0; it < 16; ++it) {
            const int row  = it * 2 + half;
            const int grow = m0 + row;
            v4 qk = *(const v4*)&qkS[row][gn0];
            const float doo = dOs[l][row];
            const float mM  = mMs[row];
            const float cM  = -NEGV * (1.0f - mM);
            v4 lv, pv;
#pragma unroll
            for (int j = 0; j < 4; ++j) {
                float v = qk[j] + de[j] + doo;
                v = v * mM + cM;            // == v*m1 - NEG*(1-m1), exact for m=1
                v = v * mNv[j] + cN[j];
                if (grow > gn0 + j) v -= NEGV;   // strict lower triangle
                lv[j] = v;
                pv[j] = __builtin_amdgcn_rcpf(1.0f + __expf(-v));
            }
            const size_t base = lbase + (size_t)row * SEQ;
            __builtin_nontemporal_store(lv, (v4*)&outL[base]);
            __builtin_nontemporal_store(pv, (v4*)&outP[base]);
        }
    }
}

extern "C" void kernel_launch(void* const* d_in, const int* in_sizes, int n_in,
                              void* d_out, int out_size, void* d_ws, size_t ws_size,
                              hipStream_t stream) {
    (void)in_sizes; (void)n_in; (void)out_size; (void)ws_size;
    const float* x    = (const float*)d_in[0];
    const int*   mask = (const int*)d_in[1];
    const float* w1   = (const float*)d_in[2];
    const float* b1   = (const float*)d_in[3];
    const float* w2   = (const float*)d_in[4];
    const float* b2   = (const float*)d_in[5];

    float* ws = (float*)d_ws;
    float* qw    = ws;                       // 16*512*64  = 524288 floats
    float* kw    = ws + 524288;              // 524288 floats
    float* dense = ws + 1048576;             // 16*40*512  = 327680 floats

    float* outL = (float*)d_out;
    float* outP = outL + (size_t)LOGITS_ELEMS;

    prep_kernel<<<dim3(3, 256), 128, 0, stream>>>(x, w1, b1, w2, b2, qw, kw, dense);
    fused_kernel<<<dim3(16, 16), 256, 0, stream>>>(qw, kw, dense, mask, outL, outP);
}

// Round 2
// 728.806 us; speedup vs baseline: 1.0453x; 1.0453x over previous
//
#include <hip/hip_runtime.h>

typedef float v4 __attribute__((ext_vector_type(4)));
typedef float v2 __attribute__((ext_vector_type(2)));
typedef int  iv4 __attribute__((ext_vector_type(4)));

#define NEGV 1000000000000.0f
#define SEQ 512
#define NL 20
#define LOGITS_ELEMS (16 * 20 * 512 * 512)   // 83,886,080

// ---------------------------------------------------------------------------
// Kernel 1 (unchanged from the 734 us baseline): out = x @ [w1|w2] + [b1|b2],
// RoPE the w1-half into qw,kw (deinterleaved), store w2-half transposed/2 as
// dense[b][40][S]. BM=32 rows, BN=64 cols per block; jb=0,1 -> w1, jb=2 -> w2.
// ---------------------------------------------------------------------------
__global__ __launch_bounds__(256)
void prep_kernel(const float* __restrict__ x, const float* __restrict__ w1,
                 const float* __restrict__ b1, const float* __restrict__ w2,
                 const float* __restrict__ b2,
                 float* __restrict__ qw, float* __restrict__ kw,
                 float* __restrict__ dense)
{
    __shared__ float xs[32][36];    // pad 36: 16B-aligned rows, conflict-free
    __shared__ float wsm[32][64];   // [k][n]

    const int tid = threadIdx.x;
    const int jb = blockIdx.x;           // 0..2
    const int m0 = blockIdx.y * 32;      // global row block
    const int j0 = jb * 64;

    const int tx = tid & 15;             // n/4
    const int ty = tid >> 4;             // 0..15, rows ty and ty+16

    const int sxm = tid >> 3;            // 0..31
    const int sxk = (tid & 7) * 4;       // 0..28
    const int swk = tid >> 3;            // 0..31 (k)
    const int swn = (tid & 7) * 8;       // 0..56 (n)

    float acc0[4] = {0.f, 0.f, 0.f, 0.f};
    float acc1[4] = {0.f, 0.f, 0.f, 0.f};

    for (int k0 = 0; k0 < 768; k0 += 32) {
        v4 xa = *(const v4*)&x[(size_t)(m0 + sxm) * 768 + k0 + sxk];
        v4 wa, wb;
        if (jb < 2) {
            wa = *(const v4*)&w1[(size_t)(k0 + swk) * 128 + j0 + swn];
            wb = *(const v4*)&w1[(size_t)(k0 + swk) * 128 + j0 + swn + 4];
        } else if (swn < 40) {
            wa = *(const v4*)&w2[(size_t)(k0 + swk) * 40 + swn];
            wb = *(const v4*)&w2[(size_t)(k0 + swk) * 40 + swn + 4];
        } else {
            wa = 0.0f; wb = 0.0f;
        }
        __syncthreads();
        *(v4*)&xs[sxm][sxk] = xa;
        *(v4*)&wsm[swk][swn] = wa;
        *(v4*)&wsm[swk][swn + 4] = wb;
        __syncthreads();
#pragma unroll
        for (int k = 0; k < 32; k += 4) {
            v4 a0 = *(const v4*)&xs[ty][k];
            v4 a1 = *(const v4*)&xs[ty + 16][k];
            v4 bv0 = *(const v4*)&wsm[k + 0][tx * 4];
            v4 bv1 = *(const v4*)&wsm[k + 1][tx * 4];
            v4 bv2 = *(const v4*)&wsm[k + 2][tx * 4];
            v4 bv3 = *(const v4*)&wsm[k + 3][tx * 4];
#pragma unroll
            for (int j = 0; j < 4; ++j) {
                acc0[j] += a0[0] * bv0[j] + a0[1] * bv1[j] + a0[2] * bv2[j] + a0[3] * bv3[j];
                acc1[j] += a1[0] * bv0[j] + a1[1] * bv1[j] + a1[2] * bv2[j] + a1[3] * bv3[j];
            }
        }
    }

    if (jb < 2) {
        // cols j = j0+4tx .. +3 = {q[2p], k[2p], q[2p+1], k[2p+1]}, p = j0/4+tx
        const int p = (j0 >> 2) + tx;    // 0..31 rope pair index
        const float fr = __powf(10000.0f, (float)(-2 * p) / 64.0f);
        v4 bb = *(const v4*)&b1[j0 + tx * 4];
#pragma unroll
        for (int i = 0; i < 2; ++i) {
            const float* acc = (i == 0) ? acc0 : acc1;
            const int mrow = m0 + ty + 16 * i;       // global row = b*512+s
            const int s = mrow & 511;
            float ang = (float)s * fr;
            float sn = sinf(ang), cs = cosf(ang);
            float q0 = acc[0] + bb[0];
            float k0v = acc[1] + bb[1];
            float q1 = acc[2] + bb[2];
            float k1v = acc[3] + bb[3];
            v2 qo, ko;
            qo[0] = q0 * cs - q1 * sn;  qo[1] = q1 * cs + q0 * sn;
            ko[0] = k0v * cs - k1v * sn; ko[1] = k1v * cs + k0v * sn;
            *(v2*)&qw[(size_t)mrow * 64 + 2 * p] = qo;
            *(v2*)&kw[(size_t)mrow * 64 + 2 * p] = ko;
        }
    } else if (tx < 10) {
        // dense cols jd = 4tx..4tx+3 (0..39), store dense[b][jd][s] = (v+b2)/2
        v4 bb = *(const v4*)&b2[tx * 4];
#pragma unroll
        for (int i = 0; i < 2; ++i) {
            const float* acc = (i == 0) ? acc0 : acc1;
            const int mrow = m0 + ty + 16 * i;
            const int bi = mrow >> 9;
            const int s = mrow & 511;
#pragma unroll
            for (int j = 0; j < 4; ++j) {
                dense[(size_t)(bi * 40 + tx * 4 + j) * 512 + s] = (acc[j] + bb[j]) * 0.5f;
            }
        }
    }
}

// ---------------------------------------------------------------------------
// Kernel 2: block = (b, 32-row m-tile, 256-col n-tile); grid (2,16,16) = 512
// blocks, 61 KB LDS -> 2 blocks/CU, 8 waves/CU, whole grid co-resident.
// Phase 1: qk[32][256]/8 into LDS via 4 x 64-col chunks (round-0 micro-kernel).
// Phase 2: 20 l-planes; each wave stores 1 KB contiguous (64 lanes x v4),
// rows sequential, nontemporal (write-once data, keep L2 for kw/dense).
// ---------------------------------------------------------------------------
__global__ __launch_bounds__(256)
void fused_kernel(const float* __restrict__ qw, const float* __restrict__ kw,
                  const float* __restrict__ dense, const int* __restrict__ mask,
                  float* __restrict__ outL, float* __restrict__ outP)
{
    __shared__ float qkS[32][260];  // qk/8 strip; 260 = 4x65, rows 16B-aligned
    __shared__ float qwL[32][68];   // [m][k]
    __shared__ float kwT[64][64];   // [k][n] for one 64-col chunk
    __shared__ float dOs[20][32];   // dense odd rows over m-tile
    __shared__ float mMs[32];

    const int tid = threadIdx.x;
    const int nT0 = blockIdx.x * 256;   // n-tile origin
    const int m0  = blockIdx.y * 32;
    const int b   = blockIdx.z;

    // one-time staging: qw tile, dense odd rows, m-mask
    {
        const int m = tid >> 3, kk = (tid & 7) * 8;
        v4 a = *(const v4*)&qw[(size_t)(b * SEQ + m0 + m) * 64 + kk];
        v4 c = *(const v4*)&qw[(size_t)(b * SEQ + m0 + m) * 64 + kk + 4];
        *(v4*)&qwL[m][kk] = a;
        *(v4*)&qwL[m][kk + 4] = c;
    }
#pragma unroll
    for (int t = 0; t < 3; ++t) {
        int flat = t * 256 + tid;
        if (flat < 640) {
            int l = flat >> 5, m = flat & 31;
            dOs[l][m] = dense[(size_t)(b * 40 + 2 * l + 1) * 512 + m0 + m];
        }
    }
    if (tid < 32) mMs[tid] = (float)mask[b * SEQ + m0 + tid];

    // ---- phase 1: qk strip into LDS, 4 chunks of 64 cols ----
    const int txc = tid & 15;   // n/4 within chunk
    const int r   = tid >> 4;   // rows r, r+16
    const int kn  = tid >> 2;   // staging: n 0..63 within chunk
    const int kkk = (tid & 3) * 16;

    for (int nc = 0; nc < 4; ++nc) {
        const int n0 = nT0 + nc * 64;
        v4 kv[4];
#pragma unroll
        for (int t = 0; t < 4; ++t)
            kv[t] = *(const v4*)&kw[(size_t)(b * SEQ + n0 + kn) * 64 + kkk + 4 * t];
        __syncthreads();   // prior chunk's kwT readers done (also fences staging)
#pragma unroll
        for (int t = 0; t < 4; ++t) {
            kwT[kkk + 4 * t + 0][kn] = kv[t][0];
            kwT[kkk + 4 * t + 1][kn] = kv[t][1];
            kwT[kkk + 4 * t + 2][kn] = kv[t][2];
            kwT[kkk + 4 * t + 3][kn] = kv[t][3];
        }
        __syncthreads();

        float acc0[4] = {0.f, 0.f, 0.f, 0.f};
        float acc1[4] = {0.f, 0.f, 0.f, 0.f};
#pragma unroll
        for (int k = 0; k < 64; k += 4) {
            v4 a0 = *(const v4*)&qwL[r][k];
            v4 a1 = *(const v4*)&qwL[r + 16][k];
            v4 bv0 = *(const v4*)&kwT[k + 0][txc * 4];
            v4 bv1 = *(const v4*)&kwT[k + 1][txc * 4];
            v4 bv2 = *(const v4*)&kwT[k + 2][txc * 4];
            v4 bv3 = *(const v4*)&kwT[k + 3][txc * 4];
#pragma unroll
            for (int j = 0; j < 4; ++j) {
                acc0[j] += a0[0] * bv0[j] + a0[1] * bv1[j] + a0[2] * bv2[j] + a0[3] * bv3[j];
                acc1[j] += a1[0] * bv0[j] + a1[1] * bv1[j] + a1[2] * bv2[j] + a1[3] * bv3[j];
            }
        }
        v4 o0, o1;
#pragma unroll
        for (int j = 0; j < 4; ++j) { o0[j] = acc0[j] * 0.125f; o1[j] = acc1[j] * 0.125f; }
        *(v4*)&qkS[r][nc * 64 + txc * 4] = o0;
        *(v4*)&qkS[r + 16][nc * 64 + txc * 4] = o1;
    }
    __syncthreads();

    // ---- phase 2: stream 20 l-planes; wave = 1 KB contiguous row segment ----
    const int c    = tid & 63;       // col chunk: cols 4c..4c+3 (0..255)
    const int half = tid >> 6;       // 0..3: row offset within group-of-4
    const int gn0  = nT0 + c * 4;

    iv4 mi = *(const iv4*)&mask[b * SEQ + gn0];
    v4 mNv, cN;
#pragma unroll
    for (int j = 0; j < 4; ++j) {
        mNv[j] = (float)mi[j];
        cN[j] = -NEGV * (1.0f - mNv[j]);
    }

    for (int l = 0; l < NL; ++l) {
        v4 de = *(const v4*)&dense[(size_t)(b * 40 + 2 * l) * 512 + gn0];
        const size_t lbase = ((size_t)(b * NL + l) * SEQ + m0) * SEQ + gn0;
#pragma unroll
        for (int it = 0; it < 8; ++it) {
            const int row  = it * 4 + half;
            const int grow = m0 + row;
            v4 qk = *(const v4*)&qkS[row][c * 4];
            const float doo = dOs[l][row];
            const float mM  = mMs[row];
            const float cM  = -NEGV * (1.0f - mM);
            v4 lv, pv;
#pragma unroll
            for (int j = 0; j < 4; ++j) {
                float v = qk[j] + de[j] + doo;
                v = v * mM + cM;            // == v*m1 - NEG*(1-m1), exact for m=1
                v = v * mNv[j] + cN[j];
                if (grow > gn0 + j) v -= NEGV;   // strict lower triangle
                lv[j] = v;
                pv[j] = __builtin_amdgcn_rcpf(1.0f + __expf(-v));
            }
            const size_t base = lbase + (size_t)row * SEQ;
            __builtin_nontemporal_store(lv, (v4*)&outL[base]);
            __builtin_nontemporal_store(pv, (v4*)&outP[base]);
        }
    }
}

extern "C" void kernel_launch(void* const* d_in, const int* in_sizes, int n_in,
                              void* d_out, int out_size, void* d_ws, size_t ws_size,
                              hipStream_t stream) {
    (void)in_sizes; (void)n_in; (void)out_size; (void)ws_size;
    const float* x    = (const float*)d_in[0];
    const int*   mask = (const int*)d_in[1];
    const float* w1   = (const float*)d_in[2];
    const float* b1   = (const float*)d_in[3];
    const float* w2   = (const float*)d_in[4];
    const float* b2   = (const float*)d_in[5];

    float* ws = (float*)d_ws;
    float* qw    = ws;                       // 16*512*64  = 524288 floats
    float* kw    = ws + 524288;              // 524288 floats
    float* dense = ws + 1048576;             // 16*40*512  = 327680 floats

    float* outL = (float*)d_out;
    float* outP = outL + (size_t)LOGITS_ELEMS;

    prep_kernel<<<dim3(3, 256), 256, 0, stream>>>(x, w1, b1, w2, b2, qw, kw, dense);
    fused_kernel<<<dim3(2, 16, 16), 256, 0, stream>>>(qw, kw, dense, mask, outL, outP);
}